// Round 15
// baseline (73.948 us; speedup 1.0000x reference)
//
#include <hip/hip_runtime.h>

typedef short short8 __attribute__((ext_vector_type(8)));
typedef float f32x4 __attribute__((ext_vector_type(4)));
typedef float f32x16 __attribute__((ext_vector_type(16)));

#define BN_EPS 1e-5f
#define CUT_THRESH 1e-3f

// ws layout (bytes):
//   [0, 18432)        wbf  (9216 bf16, [kk][co][ci] ci-octet ^ ((co>>1)&3) swizzle)
//   [18432, 18688)    coef (64 f32: scl[0:32], sft[32:64])
//   [18688, +4718592) part (1024 planes x 144 tiles x 8 sub-partials f32)
#define WS_COEF 18432
#define WS_PART 18688

__device__ __forceinline__ unsigned short f2bf(float f) {
  unsigned u = __float_as_uint(f);
  u += 0x7FFFu + ((u >> 16) & 1u);  // RNE (prep only)
  return (unsigned short)(u >> 16);
}

__device__ __forceinline__ void gload_lds16(const void* g, void* l) {
  __builtin_amdgcn_global_load_lds(
      (const __attribute__((address_space(1))) unsigned int*)g,
      (__attribute__((address_space(3))) unsigned int*)l, 16, 0, 0);
}

// One-time weight conversion + BN coefficient fusion.
__global__ void prep_kernel(const float* __restrict__ wgt,
                            const float* __restrict__ bias,
                            const float* __restrict__ gamma,
                            const float* __restrict__ beta,
                            const float* __restrict__ rmean,
                            const float* __restrict__ rvar,
                            unsigned short* __restrict__ wbf,
                            float* __restrict__ coef) {
  int tid = blockIdx.x * 256 + threadIdx.x;
  if (tid < 9216) {
    int co = tid / 288;  // wgt is OIHW
    int rem = tid - co * 288;
    int ci = rem / 9;
    int kk = rem - ci * 9;
    int oct = ((ci >> 3) ^ ((co >> 1) & 3)) << 3;
    wbf[(kk * 32 + co) * 32 + oct + (ci & 7)] = f2bf(wgt[tid]);
  }
  if (tid < 32) {
    float s = gamma[tid] * rsqrtf(rvar[tid] + BN_EPS);
    coef[tid] = s;
    coef[32 + tid] = (bias[tid] - rmean[tid]) * s + beta[tid];
  }
}

// Staging (scalar tasks, R12-proven): phase-1 issues all 48 x-loads, phase-2
// packs + swizzled ds_write_b128. INTERIOR blocks skip masks/clamps.
template <bool INTERIOR>
__device__ __forceinline__ void stage_x(const float* __restrict__ xb, int r0,
                                        int c0, int tid, int m80,
                                        unsigned short* __restrict__ lx) {
  float fv[6][8];
  int lofs[6];
  int okm[6];
#pragma unroll
  for (int r = 0; r < 6; ++r) {
    int id = (r < 5) ? (r * 256 + tid) : (1280 + m80);
    int g = id & 3;
    int p = id >> 2;  // h*34 + w
    int h = p / 34;
    int w = p - h * 34;
    const float* src;
    if (INTERIOR) {
      okm[r] = -1;
      src = xb + (g * 8) * 36864 + (r0 - 1 + h) * 192 + (c0 - 1 + w);
    } else {
      int gh = r0 - 1 + h, gw = c0 - 1 + w;
      okm[r] = (((unsigned)gh < 192u) && ((unsigned)gw < 192u)) ? -1 : 0;
      int ghc = min(max(gh, 0), 191);
      int gwc = min(max(gw, 0), 191);
      src = xb + (g * 8) * 36864 + ghc * 192 + gwc;
    }
#pragma unroll
    for (int j = 0; j < 8; ++j) fv[r][j] = src[j * 36864];  // 48 loads in flight
    lofs[r] = p * 32 + ((g ^ ((w >> 1) & 3)) << 3);
  }
  __builtin_amdgcn_sched_barrier(0);  // keep packs from sinking into load issue

#pragma unroll
  for (int r = 0; r < 6; ++r) {
    unsigned pk[4];
#pragma unroll
    for (int q = 0; q < 4; ++q) {
      float f0 = fv[r][2 * q], f1 = fv[r][2 * q + 1];
      if (!INTERIOR) {
        f0 = okm[r] ? f0 : 0.f;
        f1 = okm[r] ? f1 : 0.f;
      }
      unsigned a = __float_as_uint(f0) + 0x8000u;
      unsigned c = __float_as_uint(f1) + 0x8000u;
      pk[q] = __builtin_amdgcn_perm(c, a, 0x07060302u);  // round-half-up pack
    }
    short8 v;
    reinterpret_cast<unsigned*>(&v)[0] = pk[0];
    reinterpret_cast<unsigned*>(&v)[1] = pk[1];
    reinterpret_cast<unsigned*>(&v)[2] = pk[2];
    reinterpret_cast<unsigned*>(&v)[3] = pk[3];
    *reinterpret_cast<short8*>(&lx[lofs[r]]) = v;
  }
}

// Implicit-GEMM conv 3x3 + BN + ReLU; tile 8x32 px x 32 co per 256-thr block.
// 32x32x16 MFMA (full-128B-line nt stores); LDS 40192B -> 4 blocks/CU.
__global__ __launch_bounds__(256, 4) void conv_bn_relu_kernel(
    const float* __restrict__ x,
    const unsigned short* __restrict__ wbf,
    const float* __restrict__ coef,
    float* __restrict__ out,
    float* __restrict__ part) {
  __shared__ unsigned short lx[10 * 34 * 32];  // 21760 B
  __shared__ unsigned short lw[9 * 32 * 32];   // 18432 B -> 40192 B total

  int bid = blockIdx.x;
  int orig = (bid & 7) * 576 + (bid >> 3);  // XCD-bijective: 4608 = 8*576
  int b = orig / 144;
  int t = orig - b * 144;
  int tr = t / 6, tc = t - tr * 6;
  int r0 = tr * 8, c0 = tc * 32;
  int tid = threadIdx.x;

  // ---- weights: 1152 x 16B DMA chunks ----
  {
    const short8* wsrc = reinterpret_cast<const short8*>(wbf);
    short8* wdst = reinterpret_cast<short8*>(lw);
#pragma unroll
    for (int r = 0; r < 4; ++r) gload_lds16(wsrc + r * 256 + tid, wdst + r * 256 + tid);
    if (tid < 128) gload_lds16(wsrc + 1024 + tid, wdst + 1024 + tid);
  }

  // ---- x staging ----
  const float* xb = x + b * (32 * 192 * 192);
  int m80 = tid;
  m80 = (m80 >= 160) ? m80 - 160 : m80;
  m80 = (m80 >= 80) ? m80 - 80 : m80;

  if (tr >= 1 && tr <= 22 && tc >= 1 && tc <= 4)
    stage_x<true>(xb, r0, c0, tid, m80, lx);
  else
    stage_x<false>(xb, r0, c0, tid, m80, lx);

  int lane = tid & 63;
  int wv = tid >> 6;      // wave -> rows 2wv, 2wv+1
  int w_ = lane & 31;     // D column = pixel within the 32-w tile
  int lh = lane >> 5;     // k-half selector
  int coA = lane & 31;    // A-operand row = co

  // BN coefs for this thread's 16 D-rows: co = (r&3) + 8*(r>>2) + 4*lh
  f32x4 scl4[4], sft4[4];
#pragma unroll
  for (int g = 0; g < 4; ++g) {
    scl4[g] = *reinterpret_cast<const f32x4*>(coef + g * 8 + 4 * lh);
    sft4[g] = *reinterpret_cast<const f32x4*>(coef + 32 + g * 8 + 4 * lh);
  }

  __syncthreads();

  const int akey = (coA >> 1) & 3;
  f32x16 acc[2] = {};  // one 32co x 32px tile per row rr

  // ---- MFMA loop: 9 taps x 2 rows x 2 ci-halves of 32x32x16 ----
#pragma unroll
  for (int s = 0; s < 9; ++s) {
    const int kh = s / 3, kw = s - kh * 3;
    short8 A0 = *reinterpret_cast<const short8*>(
        &lw[(s * 32 + coA) * 32 + ((lh ^ akey) << 3)]);
    short8 A1 = *reinterpret_cast<const short8*>(
        &lw[(s * 32 + coA) * 32 + (((2 + lh) ^ akey) << 3)]);
    int wl = w_ + kw;
    int bkey = (wl >> 1) & 3;
#pragma unroll
    for (int rr = 0; rr < 2; ++rr) {
      int hl = 2 * wv + rr + kh;
      const unsigned short* brow = &lx[(hl * 34 + wl) * 32];
      short8 B0 = *reinterpret_cast<const short8*>(brow + ((lh ^ bkey) << 3));
      short8 B1 = *reinterpret_cast<const short8*>(brow + (((2 + lh) ^ bkey) << 3));
      acc[rr] = __builtin_amdgcn_mfma_f32_32x32x16_bf16(A0, B0, acc[rr], 0, 0, 0);
      acc[rr] = __builtin_amdgcn_mfma_f32_32x32x16_bf16(A1, B1, acc[rr], 0, 0, 0);
    }
  }

  // ---- epilogue: BN + ReLU, full-line nt stores, per-plane max partials ----
  const int HW = 192 * 192;
  float* ob = out + b * 32 * HW;
  float pmax[16];
#pragma unroll
  for (int r = 0; r < 16; ++r) pmax[r] = 0.f;

#pragma unroll
  for (int rr = 0; rr < 2; ++rr) {
    int gr = r0 + 2 * wv + rr;
    float* rowp = ob + gr * 192 + c0 + w_;
#pragma unroll
    for (int r = 0; r < 16; ++r) {
      int co = (r & 3) + 8 * (r >> 2) + 4 * lh;  // D row (m74/m101-verified)
      float v = fmaxf(acc[rr][r] * scl4[r >> 2][r & 3] + sft4[r >> 2][r & 3], 0.f);
      __builtin_nontemporal_store(v, rowp + co * HW);
      pmax[r] = fmaxf(pmax[r], v);
    }
  }

  // reduce over 16-lane groups (columns), then one partial per (group, co)
#pragma unroll
  for (int r = 0; r < 16; ++r) {
    float v = pmax[r];
    v = fmaxf(v, __shfl_xor(v, 1, 32));
    v = fmaxf(v, __shfl_xor(v, 2, 32));
    v = fmaxf(v, __shfl_xor(v, 4, 32));
    v = fmaxf(v, __shfl_xor(v, 8, 32));
    pmax[r] = v;
  }
  if ((lane & 15) == 0) {
    int subl = (lane >> 4) & 1;
#pragma unroll
    for (int r = 0; r < 16; ++r) {
      int co = (r & 3) + 8 * (r >> 2) + 4 * lh;
      __builtin_nontemporal_store(
          pmax[r], &part[((size_t)b * 32 + co) * 1152 + t * 8 + wv * 2 + subl]);
    }
  }
}

// Per (b,co) plane: reduce 1152 contiguous partials; zero plane if < thresh.
__global__ __launch_bounds__(256) void cut_kernel(float* __restrict__ out,
                                                  const float* __restrict__ part) {
  __shared__ float r4[4];
  int p = blockIdx.x;  // b*32 + co
  const float* pp = part + (size_t)p * 1152;
  float m = 0.f;
  for (int i = threadIdx.x; i < 1152; i += 256) m = fmaxf(m, pp[i]);
#pragma unroll
  for (int k = 1; k < 64; k <<= 1) m = fmaxf(m, __shfl_xor(m, k, 64));
  if ((threadIdx.x & 63) == 0) r4[threadIdx.x >> 6] = m;
  __syncthreads();
  m = fmaxf(fmaxf(r4[0], r4[1]), fmaxf(r4[2], r4[3]));
  if (m >= CUT_THRESH) return;  // uniform; never fires on this data
  float* base = out + (size_t)p * 36864;
  for (int i = threadIdx.x; i < 36864; i += 256) base[i] = 0.f;
}

extern "C" void kernel_launch(void* const* d_in, const int* in_sizes, int n_in,
                              void* d_out, int out_size, void* d_ws, size_t ws_size,
                              hipStream_t stream) {
  const float* x     = (const float*)d_in[0];
  const float* wgt   = (const float*)d_in[1];
  const float* bias  = (const float*)d_in[2];
  const float* gamma = (const float*)d_in[3];
  const float* beta  = (const float*)d_in[4];
  const float* rmean = (const float*)d_in[5];
  const float* rvar  = (const float*)d_in[6];
  float* out = (float*)d_out;

  unsigned short* wbf  = (unsigned short*)d_ws;
  float*          coef = (float*)((char*)d_ws + WS_COEF);
  float*          part = (float*)((char*)d_ws + WS_PART);

  prep_kernel<<<36, 256, 0, stream>>>(wgt, bias, gamma, beta, rmean, rvar, wbf, coef);
  conv_bn_relu_kernel<<<4608, 256, 0, stream>>>(x, wbf, coef, out, part);
  cut_kernel<<<1024, 256, 0, stream>>>(out, part);
}

// Round 16
// 69.412 us; speedup vs baseline: 1.0654x; 1.0654x over previous
//
#include <hip/hip_runtime.h>

typedef short short8 __attribute__((ext_vector_type(8)));
typedef float f32x4 __attribute__((ext_vector_type(4)));
typedef float f32x16 __attribute__((ext_vector_type(16)));

#define BN_EPS 1e-5f
#define CUT_THRESH 1e-3f

// ws layout (bytes):
//   [0, 18432)       wbf  (9216 bf16, [kk][co][ci] ci-octet ^ ((co>>1)&3) swizzle)
//   [18432, 18688)   coef (64 f32: scl[0:32], sft[32:64])
//   [18688, +589824) part (1024 planes x 144 tile-partials f32, contiguous)
#define WS_COEF 18432
#define WS_PART 18688

__device__ __forceinline__ unsigned short f2bf(float f) {
  unsigned u = __float_as_uint(f);
  u += 0x7FFFu + ((u >> 16) & 1u);  // RNE (prep only)
  return (unsigned short)(u >> 16);
}

__device__ __forceinline__ void gload_lds16(const void* g, void* l) {
  __builtin_amdgcn_global_load_lds(
      (const __attribute__((address_space(1))) unsigned int*)g,
      (__attribute__((address_space(3))) unsigned int*)l, 16, 0, 0);
}

// One-time weight conversion + BN coefficient fusion.
__global__ void prep_kernel(const float* __restrict__ wgt,
                            const float* __restrict__ bias,
                            const float* __restrict__ gamma,
                            const float* __restrict__ beta,
                            const float* __restrict__ rmean,
                            const float* __restrict__ rvar,
                            unsigned short* __restrict__ wbf,
                            float* __restrict__ coef) {
  int tid = blockIdx.x * 256 + threadIdx.x;
  if (tid < 9216) {
    int co = tid / 288;  // wgt is OIHW
    int rem = tid - co * 288;
    int ci = rem / 9;
    int kk = rem - ci * 9;
    int oct = ((ci >> 3) ^ ((co >> 1) & 3)) << 3;
    wbf[(kk * 32 + co) * 32 + oct + (ci & 7)] = f2bf(wgt[tid]);
  }
  if (tid < 32) {
    float s = gamma[tid] * rsqrtf(rvar[tid] + BN_EPS);
    coef[tid] = s;
    coef[32 + tid] = (bias[tid] - rmean[tid]) * s + beta[tid];
  }
}

// One staging task = (row h, w-quad q, ci-octet g): 8 float4 loads, then
// 4 swizzled ds_write_b128 (one per pixel). (R13/R14-proven machinery.)
struct Task {
  f32x4 L[8];
  int pbase;
  int g, k01, k23, dcase;
  unsigned rm;
};

template <bool INT>
__device__ __forceinline__ void issue_task(int id, const float* __restrict__ xb,
                                           int r0, int c0, Task& T) {
  int g = id & 3;
  int pq = id >> 2;  // 0..89
  int h = pq / 9;
  int q = pq - h * 9;
  int gh = r0 - 1 + h;
  int B = c0 - 1 + 4 * q;
  int ghc, Bc;
  if (INT) {
    ghc = gh; Bc = B; T.rm = 1u; T.dcase = 0;
  } else {
    T.rm = ((unsigned)gh < 192u) ? 1u : 0u;
    ghc = min(max(gh, 0), 191);
    T.dcase = (B < 0) ? 1 : ((B > 188) ? 2 : 0);
    Bc = min(max(B, 0), 188);
  }
  const float* src = xb + (g * 8) * 36864 + ghc * 192 + Bc;
#pragma unroll
  for (int j = 0; j < 8; ++j)
    T.L[j] = *reinterpret_cast<const f32x4*>(src + j * 36864);
  T.pbase = (h * 36 + 4 * q) * 32;
  T.g = g;
  T.k01 = (2 * q) & 3;
  T.k23 = (2 * q + 1) & 3;
}

template <bool INT>
__device__ __forceinline__ void pack_task(const Task& T,
                                          unsigned short* __restrict__ lx) {
#pragma unroll
  for (int wi = 0; wi < 4; ++wi) {
    const int key = (wi < 2) ? 0 : 1;
    unsigned pk[4];
#pragma unroll
    for (int c = 0; c < 4; ++c) {
      float e0, e1;
      if (INT) {
        e0 = T.L[2 * c][wi];
        e1 = T.L[2 * c + 1][wi];
      } else {
        float n0 = T.L[2 * c][wi], n1 = T.L[2 * c + 1][wi];
        float l0 = (wi == 0) ? 0.f : T.L[2 * c][wi == 0 ? 0 : wi - 1];
        float l1 = (wi == 0) ? 0.f : T.L[2 * c + 1][wi == 0 ? 0 : wi - 1];
        float r0_ = (wi == 0) ? T.L[2 * c][3] : 0.f;
        float r1_ = (wi == 0) ? T.L[2 * c + 1][3] : 0.f;
        e0 = (T.dcase == 0) ? n0 : ((T.dcase == 1) ? l0 : r0_);
        e1 = (T.dcase == 0) ? n1 : ((T.dcase == 1) ? l1 : r1_);
        e0 = T.rm ? e0 : 0.f;
        e1 = T.rm ? e1 : 0.f;
      }
      unsigned a = __float_as_uint(e0) + 0x8000u;
      unsigned cc = __float_as_uint(e1) + 0x8000u;
      pk[c] = __builtin_amdgcn_perm(cc, a, 0x07060302u);
    }
    short8 v;
    reinterpret_cast<unsigned*>(&v)[0] = pk[0];
    reinterpret_cast<unsigned*>(&v)[1] = pk[1];
    reinterpret_cast<unsigned*>(&v)[2] = pk[2];
    reinterpret_cast<unsigned*>(&v)[3] = pk[3];
    int k = key ? T.k23 : T.k01;
    *reinterpret_cast<short8*>(&lx[T.pbase + wi * 32 + ((T.g ^ k) << 3)]) = v;
  }
}

// Implicit-GEMM conv 3x3 + BN + ReLU; tile 8x32 px x 32 co per 256-thr block.
// 32x32x16 MFMA, full-128B-line nt stores, block-level plane-max reduction.
__global__ __launch_bounds__(256, 3) void conv_bn_relu_kernel(
    const float* __restrict__ x,
    const unsigned short* __restrict__ wbf,
    const float* __restrict__ coef,
    float* __restrict__ out,
    float* __restrict__ part) {
  __shared__ unsigned short lx[10 * 36 * 32];  // 23040 B
  __shared__ unsigned short lw[9 * 32 * 32];   // 18432 B
  __shared__ float red[8][32];                 // 1024 B -> 42496 B total

  int bid = blockIdx.x;
  int orig = (bid & 7) * 576 + (bid >> 3);  // XCD-bijective: 4608 = 8*576
  int b = orig / 144;
  int t = orig - b * 144;
  int tr = t / 6, tc = t - tr * 6;
  int r0 = tr * 8, c0 = tc * 32;
  int tid = threadIdx.x;

  // ---- weights: 1152 x 16B DMA chunks ----
  {
    const short8* wsrc = reinterpret_cast<const short8*>(wbf);
    short8* wdst = reinterpret_cast<short8*>(lw);
#pragma unroll
    for (int r = 0; r < 4; ++r) gload_lds16(wsrc + r * 256 + tid, wdst + r * 256 + tid);
    if (tid < 128) gload_lds16(wsrc + 1024 + tid, wdst + 1024 + tid);
  }

  // ---- x staging: 360 quad-tasks ----
  const float* xb = x + b * (32 * 192 * 192);
  bool has2 = tid < 104;
  Task T0, T1;
  if (tr >= 1 && tr <= 22 && tc >= 1 && tc <= 4) {
    issue_task<true>(tid, xb, r0, c0, T0);
    if (has2) issue_task<true>(256 + tid, xb, r0, c0, T1);
    __builtin_amdgcn_sched_barrier(0);
    pack_task<true>(T0, lx);
    if (has2) pack_task<true>(T1, lx);
  } else {
    issue_task<false>(tid, xb, r0, c0, T0);
    if (has2) issue_task<false>(256 + tid, xb, r0, c0, T1);
    __builtin_amdgcn_sched_barrier(0);
    pack_task<false>(T0, lx);
    if (has2) pack_task<false>(T1, lx);
  }

  int lane = tid & 63;
  int wv = tid >> 6;      // wave -> rows 2wv, 2wv+1
  int w_ = lane & 31;     // D column = pixel within the 32-w tile
  int lh = lane >> 5;     // k-half selector
  int coA = lane & 31;    // A-operand row = co

  // BN coefs for this thread's 16 D-rows: co = (r&3) + 8*(r>>2) + 4*lh
  f32x4 scl4[4], sft4[4];
#pragma unroll
  for (int g = 0; g < 4; ++g) {
    scl4[g] = *reinterpret_cast<const f32x4*>(coef + g * 8 + 4 * lh);
    sft4[g] = *reinterpret_cast<const f32x4*>(coef + 32 + g * 8 + 4 * lh);
  }

  __syncthreads();

  const int akey = (coA >> 1) & 3;
  f32x16 acc[2] = {};  // one 32co x 32px tile per row rr

  // ---- MFMA loop: 9 taps x 2 rows x 2 ci-halves of 32x32x16 ----
#pragma unroll
  for (int s = 0; s < 9; ++s) {
    const int kh = s / 3, kw = s - kh * 3;
    short8 A0 = *reinterpret_cast<const short8*>(
        &lw[(s * 32 + coA) * 32 + ((lh ^ akey) << 3)]);
    short8 A1 = *reinterpret_cast<const short8*>(
        &lw[(s * 32 + coA) * 32 + (((2 + lh) ^ akey) << 3)]);
    int wl = w_ + kw;
    int bkey = (wl >> 1) & 3;
#pragma unroll
    for (int rr = 0; rr < 2; ++rr) {
      int hl = 2 * wv + rr + kh;
      const unsigned short* brow = &lx[(hl * 36 + wl) * 32];
      short8 B0 = *reinterpret_cast<const short8*>(brow + ((lh ^ bkey) << 3));
      short8 B1 = *reinterpret_cast<const short8*>(brow + (((2 + lh) ^ bkey) << 3));
      acc[rr] = __builtin_amdgcn_mfma_f32_32x32x16_bf16(A0, B0, acc[rr], 0, 0, 0);
      acc[rr] = __builtin_amdgcn_mfma_f32_32x32x16_bf16(A1, B1, acc[rr], 0, 0, 0);
    }
  }

  // ---- epilogue: BN + ReLU, full-line nt stores, per-plane max partials ----
  const int HW = 192 * 192;
  float* ob = out + b * 32 * HW;
  float pmax[16];
#pragma unroll
  for (int r = 0; r < 16; ++r) pmax[r] = 0.f;

#pragma unroll
  for (int rr = 0; rr < 2; ++rr) {
    int gr = r0 + 2 * wv + rr;
    float* rowp = ob + gr * 192 + c0 + w_;
#pragma unroll
    for (int r = 0; r < 16; ++r) {
      int co = (r & 3) + 8 * (r >> 2) + 4 * lh;  // D row (m74/m101-verified)
      float v = fmaxf(acc[rr][r] * scl4[r >> 2][r & 3] + sft4[r >> 2][r & 3], 0.f);
      __builtin_nontemporal_store(v, rowp + co * HW);
      pmax[r] = fmaxf(pmax[r], v);
    }
  }

  // 16-lane butterfly -> red[8][32] -> block reduce -> ONE partial per (blk,co)
#pragma unroll
  for (int r = 0; r < 16; ++r) {
    float v = pmax[r];
    v = fmaxf(v, __shfl_xor(v, 1, 32));
    v = fmaxf(v, __shfl_xor(v, 2, 32));
    v = fmaxf(v, __shfl_xor(v, 4, 32));
    v = fmaxf(v, __shfl_xor(v, 8, 32));
    pmax[r] = v;
  }
  if ((lane & 15) == 0) {
    int subl = (lane >> 4) & 1;
#pragma unroll
    for (int r = 0; r < 16; ++r) {
      int co = (r & 3) + 8 * (r >> 2) + 4 * lh;
      red[wv * 2 + subl][co] = pmax[r];
    }
  }
  __syncthreads();
  if (tid < 32) {
    float mx = red[0][tid];
#pragma unroll
    for (int g = 1; g < 8; ++g) mx = fmaxf(mx, red[g][tid]);
    __builtin_nontemporal_store(mx, &part[((size_t)b * 32 + tid) * 144 + t]);
  }
}

// Per (b,co) plane: reduce 144 contiguous partials; zero plane if < thresh.
__global__ __launch_bounds__(256) void cut_kernel(float* __restrict__ out,
                                                  const float* __restrict__ part) {
  __shared__ float r4[4];
  int p = blockIdx.x;  // b*32 + co
  const float* pp = part + (size_t)p * 144;
  float m = 0.f;
  if (threadIdx.x < 144) m = pp[threadIdx.x];
#pragma unroll
  for (int k = 1; k < 64; k <<= 1) m = fmaxf(m, __shfl_xor(m, k, 64));
  if ((threadIdx.x & 63) == 0) r4[threadIdx.x >> 6] = m;
  __syncthreads();
  m = fmaxf(fmaxf(r4[0], r4[1]), fmaxf(r4[2], r4[3]));
  if (m >= CUT_THRESH) return;  // uniform; never fires on this data
  float* base = out + (size_t)p * 36864;
  for (int i = threadIdx.x; i < 36864; i += 256) base[i] = 0.f;
}

extern "C" void kernel_launch(void* const* d_in, const int* in_sizes, int n_in,
                              void* d_out, int out_size, void* d_ws, size_t ws_size,
                              hipStream_t stream) {
  const float* x     = (const float*)d_in[0];
  const float* wgt   = (const float*)d_in[1];
  const float* bias  = (const float*)d_in[2];
  const float* gamma = (const float*)d_in[3];
  const float* beta  = (const float*)d_in[4];
  const float* rmean = (const float*)d_in[5];
  const float* rvar  = (const float*)d_in[6];
  float* out = (float*)d_out;

  unsigned short* wbf  = (unsigned short*)d_ws;
  float*          coef = (float*)((char*)d_ws + WS_COEF);
  float*          part = (float*)((char*)d_ws + WS_PART);

  prep_kernel<<<36, 256, 0, stream>>>(wgt, bias, gamma, beta, rmean, rvar, wbf, coef);
  conv_bn_relu_kernel<<<4608, 256, 0, stream>>>(x, wbf, coef, out, part);
  cut_kernel<<<1024, 256, 0, stream>>>(out, part);
}